// Round 10
// baseline (122.072 us; speedup 1.0000x reference)
//
#include <hip/hip_runtime.h>
#include <stdint.h>

#define GMAX 128
#define TK 128            // FG_ROIS_PER_IMAGE = BG_ROIS_PER_IMAGE = 128
#define NBINS 4096
#define CAND_MAX 4096
#define NUM_CLASSES 21
#define NCELL 16          // 16x16 cells of 64px covering [0,1024)
#define CINV 0.015625f    // 1/64, exact power of two

typedef float f32x4u __attribute__((ext_vector_type(4), aligned(4)));

// ---------------------------------------------------------------------------
// JAX threefry2x32 block cipher (key = [hi32(seed), lo32(seed)] = [0, 42])
// ---------------------------------------------------------------------------
__device__ __forceinline__ void threefry2x32(uint32_t k0, uint32_t k1,
                                             uint32_t& x0, uint32_t& x1) {
  uint32_t ks0 = k0, ks1 = k1, ks2 = k0 ^ k1 ^ 0x1BD11BDAu;
  x0 += ks0; x1 += ks1;
#define TF_ROUND(r) { x0 += x1; x1 = (x1 << (r)) | (x1 >> (32 - (r))); x1 ^= x0; }
  TF_ROUND(13) TF_ROUND(15) TF_ROUND(26) TF_ROUND(6)
  x0 += ks1; x1 += ks2 + 1u;
  TF_ROUND(17) TF_ROUND(29) TF_ROUND(16) TF_ROUND(24)
  x0 += ks2; x1 += ks0 + 2u;
  TF_ROUND(13) TF_ROUND(15) TF_ROUND(26) TF_ROUND(6)
  x0 += ks0; x1 += ks1 + 3u;
  TF_ROUND(17) TF_ROUND(29) TF_ROUND(16) TF_ROUND(24)
  x0 += ks1; x1 += ks2 + 4u;
  TF_ROUND(13) TF_ROUND(15) TF_ROUND(26) TF_ROUND(6)
  x0 += ks2; x1 += ks0 + 5u;
#undef TF_ROUND
}

// ---------------------------------------------------------------------------
// Kernel 0 (r14): PREP — replaces the hipMemsetAsync dispatch. Zeros meta
// (256B) + hist (32KB) AND builds the 16x16 cell -> GT bitmask table
// (2 x uint64 per cell). GT extents padded by 2px: strictly conservative vs
// the +1-pixel IoU convention (iw>0 requires gx1 <= bx2+1), so every pair
// with nonzero IoU is guaranteed to be a candidate; extra candidates only
// contribute exact +0.0 which never perturbs the argmax (strict >).
// ---------------------------------------------------------------------------
__global__ void __launch_bounds__(512)
prep_kernel(const float* __restrict__ gt_boxes,
            uint32_t* __restrict__ hist, int* __restrict__ meta,
            uint64_t* __restrict__ cellm) {
  const int b = blockIdx.x, t = threadIdx.x;
  if (b > 0) {                         // blocks 1..16: zero hist (16*512=8192)
    const int idx = (b - 1) * 512 + t;
    if (idx < 2 * NBINS) hist[idx] = 0;
    return;
  }
  if (t < 64) meta[t] = 0;
  if (t < 256) {
    const float4* __restrict__ gt4 = reinterpret_cast<const float4*>(gt_boxes);
    const int cx = t & 15, cy = t >> 4;
    const float x0 = cx * 64.0f, x1 = x0 + 64.0f;
    const float y0 = cy * 64.0f, y1 = y0 + 64.0f;
    uint64_t m0 = 0, m1 = 0;
    for (int g = 0; g < GMAX; ++g) {
      float4 gb = gt4[g];              // uniform -> s_load
      bool ov = (gb.x - 2.0f <= x1) && (gb.z + 2.0f >= x0) &&
                (gb.y - 2.0f <= y1) && (gb.w + 2.0f >= y0);
      if (ov) { if (g < 64) m0 |= 1ull << g; else m1 |= 1ull << (g - 64); }
    }
    cellm[2 * t]     = m0;
    cellm[2 * t + 1] = m1;
  }
}

// ---------------------------------------------------------------------------
// Kernel 1 (r14): SPATIAL-BINNED score. 1 thread per ROI. Per ROI: OR the
// cell masks its box touches (<=25 cells, 1 ds_read_b128 each), then pop
// candidate GT bits in ASCENDING g and run the bit-identical IoU sequence
// only on candidates (~9 avg vs 128). Non-candidates have exactly ov=+0.0
// (conservative masks), so best=0/bi=0 init + strict > reproduces
// jnp.argmax first-max EXACTLY (all-zero row -> 0; positive ties keep the
// first). ~14x less VALU than the r12 full loop. Threefry + score write +
// hist atomics and the r8-verified 256-thread threshold tail are verbatim.
// meta: [0]=cnt_fg [1]=cnt_bg [2]=done_score [4]=bth_fg [5]=bth_bg
// ---------------------------------------------------------------------------
__global__ void __launch_bounds__(256)
score_kernel(const float* __restrict__ all_rois,   // [N,5]
             const float* __restrict__ gt_boxes,   // [G,4]
             const uint64_t* __restrict__ cellm,   // [256*2]
             uint32_t* __restrict__ score,         // [M]
             uint32_t* __restrict__ hist,          // [2*NBINS] fg|bg
             int* __restrict__ meta,
             int N, int M) {
  __shared__ float4 sbox[GMAX];
  __shared__ float sga[GMAX];
  __shared__ __align__(16) uint64_t scell[512];
  const int t = threadIdx.x;
  const float4* __restrict__ gt4 = reinterpret_cast<const float4*>(gt_boxes);
  if (t < GMAX) {
    float4 b = gt4[t];
    sbox[t] = b;
    sga[t] = __fmul_rn(__fadd_rn(__fsub_rn(b.z, b.x), 1.0f),
                       __fadd_rn(__fsub_rn(b.w, b.y), 1.0f));
  }
  scell[t]       = cellm[t];
  scell[256 + t] = cellm[256 + t];
  __syncthreads();

  const int i = blockIdx.x * 256 + t;
  const bool active = (i < M);
  float bx1 = 0.0f, by1 = 0.0f, bx2 = 0.0f, by2 = 0.0f;
  if (active) {
    if (i < N) {
      f32x4u v = *reinterpret_cast<const f32x4u*>(all_rois + (size_t)i * 5 + 1);
      bx1 = v.x; by1 = v.y; bx2 = v.z; by2 = v.w;
    } else {
      float4 b = sbox[i - N];
      bx1 = b.x; by1 = b.y; bx2 = b.z; by2 = b.w;
    }
  }
  const float area = __fmul_rn(__fadd_rn(__fsub_rn(bx2, bx1), 1.0f),
                               __fadd_rn(__fsub_rn(by2, by1), 1.0f));

  // gather candidate mask from covered cells (coords >= 0, trunc == floor)
  uint64_t m0 = 0, m1 = 0;
  if (active) {
    int cx0 = (int)(bx1 * CINV), cx1 = (int)(bx2 * CINV);
    int cy0 = (int)(by1 * CINV), cy1 = (int)(by2 * CINV);
    if (cx1 > 15) cx1 = 15;
    if (cy1 > 15) cy1 = 15;
    for (int cy = cy0; cy <= cy1; ++cy)
      for (int cx = cx0; cx <= cx1; ++cx) {
        const int c = (cy << 4) + cx;
        ulonglong2 p = *reinterpret_cast<const ulonglong2*>(&scell[2 * c]);
        m0 |= p.x; m1 |= p.y;
      }
  }

  float best = 0.0f;                   // == implicit ov of every non-candidate
  int bi = 0;                          // all-zero row -> argmax 0
#define IOU_AT(gidx)                                                    \
  {                                                                     \
    float4 gb = sbox[gidx];                                             \
    float ga = sga[gidx];                                               \
    float ix1 = fmaxf(bx1, gb.x);                                       \
    float iy1 = fmaxf(by1, gb.y);                                       \
    float ix2 = fminf(bx2, gb.z);                                       \
    float iy2 = fminf(by2, gb.w);                                       \
    float iw = fmaxf(__fadd_rn(__fsub_rn(ix2, ix1), 1.0f), 0.0f);       \
    float ih = fmaxf(__fadd_rn(__fsub_rn(iy2, iy1), 1.0f), 0.0f);       \
    float inter = __fmul_rn(iw, ih);                                    \
    float uni = __fsub_rn(__fadd_rn(area, ga), inter);                  \
    float ov = __fdiv_rn(inter, uni); /* IEEE-rounded, matches XLA */   \
    if (ov > best) { best = ov; bi = (gidx); }                          \
  }
  while (m0) { int g = __builtin_ctzll(m0); m0 &= m0 - 1; IOU_AT(g); }
  while (m1) { int g = 64 + __builtin_ctzll(m1); m1 &= m1 - 1; IOU_AT(g); }
#undef IOU_AT

  if (active) {
    // partitionable threefry: counter (hi=0, lo=i), output = x0 ^ x1
    uint32_t c0 = 0u, c1 = (uint32_t)i;
    threefry2x32(0u, 42u, c0, c1);
    uint32_t ubits = (c0 ^ c1) >> 9;   // mantissa of u in [0,1)
    uint32_t fg = (best >= 0.5f) ? 1u : 0u;
    uint32_t bg = (!fg && best >= 0.1f) ? 1u : 0u;
    score[i] = (ubits << 9) | ((uint32_t)bi << 2) | (fg << 1) | bg;
    if (fg)      atomicAdd(&hist[ubits >> 11], 1u);
    else if (bg) atomicAdd(&hist[NBINS + (ubits >> 11)], 1u);
  }

  // ---- last-block exact threshold computation (r8-verified, 256 thr) ----
  asm volatile("s_waitcnt vmcnt(0)" ::: "memory");
  __syncthreads();
  __shared__ unsigned s_prev;
  if (t == 0) s_prev = atomicAdd((unsigned int*)&meta[2], 1u);
  __syncthreads();
  if (s_prev != gridDim.x - 1) return;

  __shared__ uint64_t gs[256];
  __shared__ int s_jstar[2];
  const int b0 = 16 * t;              // 16 bins per thread, 256*16 = 4096
  uint64_t acc = 0;
  for (int k = 0; k < 16; ++k) {
    uint32_t hf = __hip_atomic_load(&hist[b0 + k], __ATOMIC_RELAXED,
                                    __HIP_MEMORY_SCOPE_AGENT);
    uint32_t hb = __hip_atomic_load(&hist[NBINS + b0 + k], __ATOMIC_RELAXED,
                                    __HIP_MEMORY_SCOPE_AGENT);
    acc += ((uint64_t)hf << 32) | (uint64_t)hb;
  }
  gs[t] = acc;
  if (t < 2) s_jstar[t] = -1;
  __syncthreads();
  for (int d = 1; d < 256; d <<= 1) { // inclusive suffix scan
    uint64_t add = (t + d < 256) ? gs[t + d] : 0ull;
    __syncthreads();
    gs[t] += add;
    __syncthreads();
  }
  uint32_t vfg = (uint32_t)(gs[t] >> 32);
  uint32_t vbg = (uint32_t)gs[t];
  uint32_t nfg = (t < 255) ? (uint32_t)(gs[t + 1] >> 32) : 0u;
  uint32_t nbg = (t < 255) ? (uint32_t)gs[t + 1] : 0u;
  if (vfg >= (uint32_t)TK && (t == 255 || nfg < (uint32_t)TK)) s_jstar[0] = t;
  if (vbg >= (uint32_t)TK && (t == 255 || nbg < (uint32_t)TK)) s_jstar[1] = t;
  __syncthreads();
  if (t == 0) {
    for (int m = 0; m < 2; ++m) {
      int j = s_jstar[m], B = -1;
      if (j >= 0) {
        uint32_t base = 0;
        if (j < 255)
          base = (m == 0) ? (uint32_t)(gs[j + 1] >> 32) : (uint32_t)gs[j + 1];
        B = 16 * j;
        for (int b = 16 * j + 15; b >= 16 * j; --b) {
          base += __hip_atomic_load(&hist[m * NBINS + b], __ATOMIC_RELAXED,
                                    __HIP_MEMORY_SCOPE_AGENT);
          if (base >= (uint32_t)TK) { B = b; break; }
        }
      }
      meta[4 + m] = B;
    }
  }
}

// ---------------------------------------------------------------------------
// Kernel 2 (r8-verified): pure streaming filter. Thresholds from meta[4/5]
// (cross-dispatch visibility by stream ordering). Plain cand stores (read by
// the NEXT dispatch). Bth<0 => append ALL masked (fallback signal).
// ---------------------------------------------------------------------------
__global__ void __launch_bounds__(256)
compact_kernel(const uint32_t* __restrict__ score, int M,
               int* __restrict__ meta,             // [0]=cnt_fg [1]=cnt_bg
               uint64_t* __restrict__ cand) {
  const int bth[2] = {meta[4], meta[5]};
  const int base = (blockIdx.x * 256 + threadIdx.x) * 4;
  if (base >= M) return;
  uint32_t ss[4];
  int lim;
  if (base + 3 < M) {
    uint4 s4 = *reinterpret_cast<const uint4*>(score + base);
    ss[0] = s4.x; ss[1] = s4.y; ss[2] = s4.z; ss[3] = s4.w;
    lim = 4;
  } else {
    lim = M - base;
    for (int k = 0; k < lim; ++k) ss[k] = score[base + k];
  }
  for (int k = 0; k < lim; ++k) {
    uint32_t s = ss[k];
    uint32_t mb = s & 3u;
    if (!mb) continue;
    int m = (mb & 2u) ? 0 : 1;
    int B = bth[m];
    if (B >= 0 && (int)(s >> 20) < B) continue;
    int p = atomicAdd(&meta[m], 1);
    if (p < CAND_MAX)
      cand[(size_t)m * CAND_MAX + p] =
          (((uint64_t)((s >> 9) + 1u)) << 32) | (uint64_t)(~(uint32_t)(base + k));
  }
}

// ---------------------------------------------------------------------------
// Kernel 3 (r8-verified): rank-based top-TK selection. Keys ((ubits+1)<<32)|~i
// are unique, so rank = #{keys > mine} reproduces the exact descending order
// == XLA stable top_k, independent of append order. Fused finalize.
// Output layout: rois[256*5] | labels[256] | targets[256*84]
// ---------------------------------------------------------------------------
__global__ void __launch_bounds__(1024)
final_kernel(const float* __restrict__ all_rois,
             const float* __restrict__ gt_boxes,
             const int* __restrict__ gt_labels,
             const uint32_t* __restrict__ score,
             const uint64_t* __restrict__ cand_g,
             const int* __restrict__ meta,
             float* __restrict__ out, int N, int M) {
  __shared__ uint64_t cand[CAND_MAX];
  __shared__ int keep[2 * TK];
  __shared__ int fgvalid[TK];
  __shared__ float s_tx[2 * TK], s_ty[2 * TK], s_tw[2 * TK], s_th[2 * TK];
  __shared__ int s_label[2 * TK];
  const int t = threadIdx.x;

  for (int m = 0; m < 2; ++m) {
    int cnt = meta[m]; if (cnt > CAND_MAX) cnt = CAND_MAX;
    for (int p = t; p < cnt; p += 1024)
      cand[p] = cand_g[(size_t)m * CAND_MAX + p];
    __syncthreads();
    for (int p = t; p < cnt; p += 1024) {
      uint64_t key = cand[p];
      int r = 0;
      for (int j = 0; j < cnt; ++j) r += (cand[j] > key) ? 1 : 0;
      if (r < TK) {
        keep[m * TK + r] = (int)(~(uint32_t)(key & 0xFFFFFFFFull));
        if (m == 0) fgvalid[r] = 1;
      }
    }
    __syncthreads();
    if (cnt < TK && t == 0) {         // mask had <TK members: pad with lowest-
      int fill = cnt;                 // index non-masked (JAX -1.0 tie semantics)
      uint32_t mask_bit = (m == 0) ? 2u : 1u;
      for (int i2 = 0; i2 < M && fill < TK; ++i2)
        if (!(score[i2] & mask_bit)) {
          keep[m * TK + fill] = i2;
          if (m == 0) fgvalid[fill] = 0;
          fill++;
        }
    }
    __syncthreads();
  }

  const int R = 2 * TK;
  float* rois_out   = out;
  float* labels_out = out + (size_t)R * 5;
  float* bt_out     = out + (size_t)R * 5 + R;

  if (t < R) {
    const int i = keep[t];
    float rimg, rx1, ry1, rx2, ry2;
    if (i < N) {
      rimg = all_rois[(size_t)i * 5 + 0];
      rx1  = all_rois[(size_t)i * 5 + 1];
      ry1  = all_rois[(size_t)i * 5 + 2];
      rx2  = all_rois[(size_t)i * 5 + 3];
      ry2  = all_rois[(size_t)i * 5 + 4];
    } else {
      int g = i - N;
      rimg = 0.0f;
      rx1 = gt_boxes[g * 4 + 0]; ry1 = gt_boxes[g * 4 + 1];
      rx2 = gt_boxes[g * 4 + 2]; ry2 = gt_boxes[g * 4 + 3];
    }
    rois_out[t * 5 + 0] = rimg;
    rois_out[t * 5 + 1] = rx1;
    rois_out[t * 5 + 2] = ry1;
    rois_out[t * 5 + 3] = rx2;
    rois_out[t * 5 + 4] = ry2;

    const int ga = (int)((score[i] >> 2) & 127u);
    int label = (t < TK && fgvalid[t]) ? gt_labels[ga] : 0;
    labels_out[t] = (float)label;
    s_label[t] = label;

    float gx1 = gt_boxes[ga * 4 + 0], gy1 = gt_boxes[ga * 4 + 1];
    float gx2 = gt_boxes[ga * 4 + 2], gy2 = gt_boxes[ga * 4 + 3];
    float ew = rx2 - rx1 + 1.0f, eh = ry2 - ry1 + 1.0f;
    float ecx = rx1 + 0.5f * ew, ecy = ry1 + 0.5f * eh;
    float gw = gx2 - gx1 + 1.0f, gh = gy2 - gy1 + 1.0f;
    float gcx = gx1 + 0.5f * gw, gcy = gy1 + 0.5f * gh;
    s_tx[t] = (gcx - ecx) / ew;
    s_ty[t] = (gcy - ecy) / eh;
    s_tw[t] = logf(gw / ew);
    s_th[t] = logf(gh / eh);
  }
  __syncthreads();

  const int TOT = R * 4 * NUM_CLASSES;
  for (int idx = t; idx < TOT; idx += 1024) {
    int r = idx / (4 * NUM_CLASSES);
    int c = idx - r * (4 * NUM_CLASSES);
    int lab = s_label[r];
    float v = 0.0f;
    if (lab > 0 && (c >> 2) == lab) {
      int cc = c & 3;
      v = (cc == 0) ? s_tx[r] : (cc == 1) ? s_ty[r] : (cc == 2) ? s_tw[r] : s_th[r];
    }
    bt_out[idx] = v;
  }
}

// ---------------------------------------------------------------------------
extern "C" void kernel_launch(void* const* d_in, const int* in_sizes, int n_in,
                              void* d_out, int out_size, void* d_ws, size_t ws_size,
                              hipStream_t stream) {
  const float* all_rois = (const float*)d_in[0];
  const float* gt_boxes = (const float*)d_in[1];
  const int*   gt_labels = (const int*)d_in[2];
  const int N = in_sizes[0] / 5;
  const int G = in_sizes[2];
  const int M = N + G;
  (void)G;

  // workspace: [meta 256B][hist 32KB][score M*4][cand 64KB][cellmask 4KB]
  char* ws = (char*)d_ws;
  int* meta = (int*)ws;
  uint32_t* hist = (uint32_t*)(ws + 256);
  size_t off = 256 + (size_t)2 * NBINS * 4;
  uint32_t* score = (uint32_t*)(ws + off);
  off += (((size_t)M * 4) + 255) & ~(size_t)255;
  uint64_t* cand = (uint64_t*)(ws + off);
  off += (size_t)2 * CAND_MAX * 8;
  uint64_t* cellm = (uint64_t*)(ws + off);
  float* out = (float*)d_out;

  prep_kernel<<<17, 512, 0, stream>>>(gt_boxes, hist, meta, cellm);
  const int nblocks = (M + 255) / 256;
  score_kernel<<<nblocks, 256, 0, stream>>>(all_rois, gt_boxes, cellm, score,
                                            hist, meta, N, M);
  const int nb4 = ((M + 3) / 4 + 255) / 256;
  compact_kernel<<<nb4, 256, 0, stream>>>(score, M, meta, cand);
  final_kernel<<<1, 1024, 0, stream>>>(all_rois, gt_boxes, gt_labels, score,
                                       cand, meta, out, N, M);
}